// Round 3
// baseline (1918.082 us; speedup 1.0000x reference)
//
#include <hip/hip_runtime.h>
#include <math.h>

// Sinkhorn loss, B=8, S=2048, P=1024, D=2, eps=0.01, 50 iters.
// PERSISTENT-KERNEL v3.
// R1/R2 both failed with IDENTICAL absmax 3.369e-2 (== |ref| with out=0) at
// different grid sizes => the cooperative launch itself errors (swallowed):
// hipLaunchCooperativeKernel is not graph-capturable in this harness.
// Fix: plain hipLaunchKernelGGL. Co-residency comes from geometry instead of
// the API: 256 blocks on 256 CUs, 49.5KB LDS, 256 thr -> all blocks resident
// at dispatch, so the hand-rolled per-batch atomic barriers cannot deadlock.
// Kernel body identical to R2 (inner loop == proven 844us multi-launch code).
// Base-2 scaled potentials: F2 = f/(eps*ln2), G2 = g/(eps*ln2), K = 100*log2(e)
//   f elem: u = 2K*x.y + (G2[p] - K*y2[p]);  F2 = (K*x2 - log2 S) - LSE2(u)
//   g elem: u = 2K*x.y + (F2[s] - K*x2[s]);  G2 = (K*y2 + logb2) - LSE2(u)

#define BB 8
#define SS 2048
#define PP 1024
#define NEG_INF -1e9f
#define LOG2S 11.0f
#define ITERS 50
#define K2E 144.269504088896f   /* 100*log2(e) */
#define TWOK 288.539008177792f  /* 200*log2(e) */
#define NBLK 256
#define BLK_PER_BATCH 32

__device__ __forceinline__ float fexp2(float x) {
  return __builtin_amdgcn_exp2f(x);
}
__device__ __forceinline__ float flog2(float x) {
  return __builtin_amdgcn_logf(x);
}

// agent-scope coherent (cache-bypassing) accessors for cross-XCD data
__device__ __forceinline__ float coh_load(const float* p) {
  return __hip_atomic_load((float*)p, __ATOMIC_RELAXED, __HIP_MEMORY_SCOPE_AGENT);
}
__device__ __forceinline__ void coh_store(float* p, float v) {
  __hip_atomic_store(p, v, __ATOMIC_RELAXED, __HIP_MEMORY_SCOPE_AGENT);
}

// 32-block per-batch barrier; target is monotonic (32 * phase_number).
__device__ __forceinline__ void batch_barrier(int* cnt, int target) {
  __syncthreads();  // all waves drain their stores (vmcnt0) before arrival
  if (threadIdx.x == 0) {
    __hip_atomic_fetch_add(cnt, 1, __ATOMIC_RELEASE, __HIP_MEMORY_SCOPE_AGENT);
    while (__hip_atomic_load(cnt, __ATOMIC_ACQUIRE, __HIP_MEMORY_SCOPE_AGENT) <
           target)
      __builtin_amdgcn_s_sleep(2);
  }
  __syncthreads();
  __builtin_amdgcn_fence(__ATOMIC_ACQUIRE, "agent");
}

// ws layout (bytes):
//   G2    : [0,      32768)   B*P float
//   F2    : [32768,  98304)   B*S float
//   logb2 : [98304, 131072)   B*P float
//   cnt   : [131072, 135168)  8 batch counters, stride 32 ints (128 B)

__global__ __launch_bounds__(1024) void setup_kernel(
    const int* __restrict__ labels, float* __restrict__ G2,
    float* __restrict__ logb2, int* __restrict__ cnt,
    float* __restrict__ out) {
  __shared__ int c[PP];
  int b = blockIdx.x;
  int t = threadIdx.x;  // 1024 threads
  c[t] = 0;
  __syncthreads();
  atomicAdd(&c[labels[b * SS + t] & (PP - 1)], 1);
  atomicAdd(&c[labels[b * SS + PP + t] & (PP - 1)], 1);
  __syncthreads();
  int cc = c[t];
  logb2[b * PP + t] = (cc > 0) ? (flog2((float)cc) - LOG2S) : NEG_INF;
  G2[b * PP + t] = 0.0f;
  if (t == 0) {
    cnt[b << 5] = 0;
    if (b == 0) out[0] = 0.0f;
  }
}

// One row/col-group LSE tile: 128 elements per lane from LDS, then
// xor-reduce max and sum across lane groups starting at OFF0.
// Returns m + log2(s) (valid in all lanes).
template <int OFF0>
__device__ __forceinline__ float lse2_tile(const float4* cb, float k0,
                                           float k1) {
  float u[128];
  float m0 = -3.4e38f, m1 = -3.4e38f;
#pragma unroll
  for (int i = 0; i < 128; i += 4) {
    float4 a0 = cb[i], a1 = cb[i + 1], a2 = cb[i + 2], a3 = cb[i + 3];
    float u0 = fmaf(k0, a0.x, fmaf(k1, a0.y, a0.z));
    float u1 = fmaf(k0, a1.x, fmaf(k1, a1.y, a1.z));
    float u2 = fmaf(k0, a2.x, fmaf(k1, a2.y, a2.z));
    float u3 = fmaf(k0, a3.x, fmaf(k1, a3.y, a3.z));
    u[i] = u0; u[i + 1] = u1; u[i + 2] = u2; u[i + 3] = u3;
    m0 = fmaxf(fmaxf(m0, u0), u1);  // v_max3 fusion
    m1 = fmaxf(fmaxf(m1, u2), u3);
  }
  float m = fmaxf(m0, m1);
#pragma unroll
  for (int off = OFF0; off <= 32; off <<= 1)
    m = fmaxf(m, __shfl_xor(m, off, 64));
  float s0 = 0.0f, s1 = 0.0f, s2 = 0.0f, s3 = 0.0f;
#pragma unroll
  for (int i = 0; i < 128; i += 4) {
    s0 += fexp2(u[i] - m);
    s1 += fexp2(u[i + 1] - m);
    s2 += fexp2(u[i + 2] - m);
    s3 += fexp2(u[i + 3] - m);
  }
  float s = (s0 + s1) + (s2 + s3);
#pragma unroll
  for (int off = OFF0; off <= 32; off <<= 1) s += __shfl_xor(s, off, 64);
  return m + flog2(s);
}

__global__ __launch_bounds__(256) void sinkhorn_persist(
    const float* __restrict__ preds, const float* __restrict__ pos,
    const float* __restrict__ logb2, float* __restrict__ F2g,
    float* __restrict__ G2g, int* __restrict__ cnt, float* __restrict__ out) {
  __shared__ float4 shf[1032];  // (y0, y1, qy = G2 - K*y2, pad), +16B pad /128
  __shared__ float4 shg[2064];  // (x0, x1, qx = F2 - K*x2, pad), +16B pad /128
  __shared__ float spart;
  const int t = threadIdx.x;
  const int blk = blockIdx.x;   // 256 blocks
  const int bb = blk >> 5;      // 32 blocks per batch
  int* mycnt = cnt + (bb << 5);
  const float2* pos2 = (const float2*)pos;
  const float2* preds2 = (const float2*)preds;
  float* G2b = G2g + (bb << 10);
  float* F2b = F2g + (bb << 11);

  // ---- persistent init: x/y constants into LDS + K-scaled norms in regs
  float yr2[4], xr2[8];
#pragma unroll
  for (int k = 0; k < 4; ++k) {
    int e = t + (k << 8);
    float2 y = pos2[(bb << 10) + e];
    yr2[k] = y.x * y.x + y.y * y.y;
    shf[e + (e >> 7)] = make_float4(y.x, y.y, 0.0f, 0.0f);
  }
#pragma unroll
  for (int k = 0; k < 8; ++k) {
    int e = t + (k << 8);
    float2 x = preds2[(bb << 11) + e];
    xr2[k] = x.x * x.x + x.y * x.y;
    shg[e + (e >> 7)] = make_float4(x.x, x.y, 0.0f, 0.0f);
  }

  const int w = t >> 6, lane = t & 63;
  // f-phase: block owns 64 rows; per pass 32 rows (8/wave), 8 chunks x 128 cols
  const int frow0 = (blk << 6) + (w << 3) + (lane & 7);
  const float4* fcb = shf + (lane >> 3) * 129;
  float2 fxA = preds2[frow0];
  float2 fxB = preds2[frow0 + 32];
  const float fkx0A = TWOK * fxA.x, fkx1A = TWOK * fxA.y;
  const float fkx0B = TWOK * fxB.x, fkx1B = TWOK * fxB.y;
  const float fc0A = fmaf(K2E, fxA.x * fxA.x + fxA.y * fxA.y, -LOG2S);
  const float fc0B = fmaf(K2E, fxB.x * fxB.x + fxB.y * fxB.y, -LOG2S);
  // g-phase: block owns 32 cols; per pass 16 cols (4/wave), 16 chunks x 128 rows
  const int gcol0 = (blk << 5) + (w << 2) + (lane & 3);
  const float4* gcb = shg + (lane >> 2) * 129;
  float2 gyA = pos2[gcol0];
  float2 gyB = pos2[gcol0 + 16];
  const float gk0A = TWOK * gyA.x, gk1A = TWOK * gyA.y;
  const float gk0B = TWOK * gyB.x, gk1B = TWOK * gyB.y;
  const float gc0A = fmaf(K2E, gyA.x * gyA.x + gyA.y * gyA.y, logb2[gcol0]);
  const float gc0B = fmaf(K2E, gyB.x * gyB.x + gyB.y * gyB.y, logb2[gcol0 + 16]);

  int target = 0;

  for (int it = 0; it < ITERS; ++it) {
    // ---- stage qy = G2 - K*y2 (4KB coherent reads; same-thread LDS slots)
#pragma unroll
    for (int k = 0; k < 4; ++k) {
      int e = t + (k << 8);
      shf[e + (e >> 7)].z = fmaf(-K2E, yr2[k], coh_load(&G2b[e]));
    }
    __syncthreads();
    {
      float lA = lse2_tile<8>(fcb, fkx0A, fkx1A);
      float lB = lse2_tile<8>(fcb, fkx0B, fkx1B);
      if (lane < 8) {
        coh_store(&F2g[frow0], fc0A - lA);
        coh_store(&F2g[frow0 + 32], fc0B - lB);
      }
    }
    target += BLK_PER_BATCH;
    batch_barrier(mycnt, target);

    // ---- stage qx = F2 - K*x2 (8KB coherent reads)
#pragma unroll
    for (int k = 0; k < 8; ++k) {
      int e = t + (k << 8);
      shg[e + (e >> 7)].z = fmaf(-K2E, xr2[k], coh_load(&F2b[e]));
    }
    __syncthreads();
    {
      float lA = lse2_tile<4>(gcb, gk0A, gk1A);
      float lB = lse2_tile<4>(gcb, gk0B, gk1B);
      if (lane < 4) {
        coh_store(&G2g[gcol0], gc0A - lA);
        coh_store(&G2g[gcol0 + 16], gc0B - lB);
      }
    }
    target += BLK_PER_BATCH;
    batch_barrier(mycnt, target);
  }

  // ---- fused final: restage qy with final G2, rowsum over own 64 rows
  if (t == 0) spart = 0.0f;
#pragma unroll
  for (int k = 0; k < 4; ++k) {
    int e = t + (k << 8);
    shf[e + (e >> 7)].z = fmaf(-K2E, yr2[k], coh_load(&G2b[e]));
  }
  __syncthreads();
  float acc = 0.0f;
#pragma unroll
  for (int rr = 0; rr < 16; ++rr) {
    int row = (blk << 6) + (w << 4) + rr;
    float2 x = preds2[row];
    float x2 = x.x * x.x + x.y * x.y;
    float qx = fmaf(-K2E, x2, coh_load(&F2g[row]));
#pragma unroll
    for (int i = 0; i < 16; ++i) {
      int p = (i << 6) + lane;
      float4 a = shf[p + (p >> 7)];
      float y2 = fmaf(a.x, a.x, a.y * a.y);
      float tt = fmaf(x.y, a.y, x.x * a.x);
      float c = fmaxf(x2 + y2 - 2.0f * tt, 0.0f);  // clamped cost
      float v2 = fmaf(TWOK, tt, a.z + qx);         // -K*C' + F2 + G2 (base-2)
      acc = fmaf(fexp2(v2), c, acc);               // c==0 kills C'<0 case
    }
  }
#pragma unroll
  for (int off = 32; off; off >>= 1) acc += __shfl_xor(acc, off, 64);
  if (lane == 0) atomicAdd(&spart, acc);
  __syncthreads();
  if (t == 0) atomicAdd(out, spart * (1.0f / (float)BB));
}

extern "C" void kernel_launch(void* const* d_in, const int* in_sizes, int n_in,
                              void* d_out, int out_size, void* d_ws,
                              size_t ws_size, hipStream_t stream) {
  const float* preds = (const float*)d_in[0];  // [B,S,2]
  const int* labels = (const int*)d_in[1];     // [B,S]
  const float* pos = (const float*)d_in[2];    // [B,P,2]
  float* out = (float*)d_out;
  char* ws = (char*)d_ws;
  float* G2 = (float*)(ws);
  float* F2 = (float*)(ws + 32768);
  float* logb2 = (float*)(ws + 98304);
  int* cnt = (int*)(ws + 131072);

  hipLaunchKernelGGL(setup_kernel, dim3(BB), dim3(1024), 0, stream, labels, G2,
                     logb2, cnt, out);
  hipLaunchKernelGGL(sinkhorn_persist, dim3(NBLK), dim3(256), 0, stream,
                     preds, pos, logb2, F2, G2, cnt, out);
}